// Round 1
// baseline (720.848 us; speedup 1.0000x reference)
//
#include <hip/hip_runtime.h>
#include <float.h>

// ---------------- workspace layout (float offsets) ----------------
static constexpr size_t OFF_H1    = 0;          // 8*256*1024 = 2,097,152 (dead after conv2)
static constexpr size_t OFF_H2    = 2097152;    // 8*64*2048  = 1,048,576
static constexpr size_t OFF_FEAT  = 3145728;    // feat2a (8*64*2048*4) then h4 (8*256*2048) = 4,194,304
static constexpr size_t OFF_FINAL = 7340032;    // 8*192*2048 = 3,145,728
static constexpr size_t OFF_Y     = 10485760;   // 1,048,576
static constexpr size_t OFF_Z     = 11534336;   // 1,048,576
static constexpr size_t OFF_XX    = 12582912;   // 8*2048 = 16,384
static constexpr size_t OFF_G     = 12599296;   // 8*64 = 512
static constexpr size_t OFF_G3B   = 12599808;   // 8*128 = 1024
static constexpr size_t OFF_IDX   = 12600832;   // 8*2048*4 ints = 65,536
static constexpr size_t WS_FLOATS = 12666368;   // ~48.3 MB

// =================================================================
// Generic tiled fp32 GEMM: out[b,o,n] = act((sum_c W[o,c]*in[b,c,n])*scale + bias)
// 64o x 64n tile per block, 4x4 micro-tile per thread, K chunked by 16.
// MAXK=true: n-dim is (n,k) pairs with k fastest; epilogue maxes over each
// thread's 4 contiguous n' (= the 4 k of one n) and writes one float.
// =================================================================
template<int C, bool MAXK>
__global__ __launch_bounds__(256) void gemm_cn(
    const float* __restrict__ W, int wstride,
    const float* __restrict__ scale, const float* __restrict__ bias, int do_relu,
    const float* __restrict__ in, size_t ibstride, int irstride,
    float* __restrict__ out, size_t obstride, int orstride)
{
    const int nB = blockIdx.x * 64;
    const int oB = blockIdx.y * 64;
    const int b  = blockIdx.z;
    const float* inb = in + (size_t)b * ibstride;
    float* outb = out + (size_t)b * obstride;
    const int t  = threadIdx.x;
    const int tn = t & 15, to = t >> 4;

    __shared__ float Ws[16][64];   // [c][o]
    __shared__ float Is[16][64];   // [c][n]

    float acc[4][4];
#pragma unroll
    for (int i = 0; i < 4; ++i)
#pragma unroll
        for (int j = 0; j < 4; ++j) acc[i][j] = 0.f;

    const int wo = t & 63, wc = t >> 6;   // weight loader: 64 o x 4 c-quads
    for (int c0 = 0; c0 < C; c0 += 16) {
        float4 wv = *(const float4*)(W + (size_t)(oB + wo) * wstride + c0 + wc * 4);
        float4 iv = *(const float4*)(inb + (size_t)(c0 + to) * irstride + nB + tn * 4);
        __syncthreads();   // previous chunk fully consumed
        Ws[wc * 4 + 0][wo] = wv.x;
        Ws[wc * 4 + 1][wo] = wv.y;
        Ws[wc * 4 + 2][wo] = wv.z;
        Ws[wc * 4 + 3][wo] = wv.w;
        *(float4*)&Is[to][tn * 4] = iv;
        __syncthreads();
#pragma unroll
        for (int c = 0; c < 16; ++c) {
            float4 av = *(const float4*)&Ws[c][to * 4];
            float4 bv = *(const float4*)&Is[c][tn * 4];
            acc[0][0] += av.x * bv.x; acc[0][1] += av.x * bv.y; acc[0][2] += av.x * bv.z; acc[0][3] += av.x * bv.w;
            acc[1][0] += av.y * bv.x; acc[1][1] += av.y * bv.y; acc[1][2] += av.y * bv.z; acc[1][3] += av.y * bv.w;
            acc[2][0] += av.z * bv.x; acc[2][1] += av.z * bv.y; acc[2][2] += av.z * bv.z; acc[2][3] += av.z * bv.w;
            acc[3][0] += av.w * bv.x; acc[3][1] += av.w * bv.y; acc[3][2] += av.w * bv.z; acc[3][3] += av.w * bv.w;
        }
    }

#pragma unroll
    for (int i = 0; i < 4; ++i) {
        const int o = oB + to * 4 + i;
        const float s  = scale ? scale[o] : 1.0f;
        const float bb = bias  ? bias[o]  : 0.0f;
        if constexpr (MAXK) {
            float v = -FLT_MAX;
#pragma unroll
            for (int j = 0; j < 4; ++j) {
                float u = fmaxf(acc[i][j] * s + bb, 0.f);
                v = fmaxf(v, u);
            }
            outb[(size_t)o * orstride + (nB >> 2) + tn] = v;
        } else {
            float4 r;
            r.x = acc[i][0] * s + bb;
            r.y = acc[i][1] * s + bb;
            r.z = acc[i][2] * s + bb;
            r.w = acc[i][3] * s + bb;
            if (do_relu) {
                r.x = fmaxf(r.x, 0.f); r.y = fmaxf(r.y, 0.f);
                r.z = fmaxf(r.z, 0.f); r.w = fmaxf(r.w, 0.f);
            }
            *(float4*)(outb + (size_t)o * orstride + nB + tn * 4) = r;
        }
    }
}

// ---- top-4 insertion, list sorted by (value desc, index asc); equal value
// keeps lower index (jax.lax.top_k tie semantics) ----
static __device__ __forceinline__ void ins4(float v, int m, float bv[4], int bi[4])
{
#pragma unroll
    for (int s = 0; s < 4; ++s) {
        bool better = (v > bv[s]) || (v == bv[s] && m < bi[s]);
        float tv = bv[s]; int tm = bi[s];
        bv[s] = better ? v : bv[s];
        bi[s] = better ? m : bi[s];
        v = better ? tv : v;
        m = better ? tm : m;
    }
}

// =================================================================
// Fused pairwise-distance + top-4 kNN.
// pd[n,m] = fl(fl(2*dot(h_n,h_m) - xx[m]) - xx[n])  (reference op order)
// Block: 256 thr = 4 waves; each wave owns 16 rows; lane = 4 rows x 4 m.
// m swept in 64-wide LDS tiles; per-row top-4 kept in registers; final
// 16-way cross-lane merge through LDS.
// =================================================================
__global__ __launch_bounds__(256) void knn_topk(const float* __restrict__ h2,
                                                const float* __restrict__ xx,
                                                int* __restrict__ idxout)
{
    const int b  = blockIdx.y;
    const int n0 = blockIdx.x * 64;
    const int t  = threadIdx.x;
    const int lane = t & 63;
    const int w    = t >> 6;
    const int li   = lane >> 4;          // 0..3 row-quad
    const int lj   = lane & 15;          // 0..15 m-group
    const int rowb = w * 16 + li * 4;    // block-relative row base

    __shared__ float rows[64][64];   // [c][row]
    __shared__ float mt[64][64];     // [c][m]
    __shared__ float mxx[64];

    const float* hb = h2 + (size_t)b * 64 * 2048;
#pragma unroll
    for (int it = 0; it < 16; ++it) {
        int idx = it * 256 + t;
        rows[idx >> 6][idx & 63] = hb[(size_t)(idx >> 6) * 2048 + n0 + (idx & 63)];
    }
    float xn[4];
#pragma unroll
    for (int r = 0; r < 4; ++r) xn[r] = xx[(size_t)b * 2048 + n0 + rowb + r];

    float bv[4][4]; int bi[4][4];
#pragma unroll
    for (int r = 0; r < 4; ++r)
#pragma unroll
        for (int s = 0; s < 4; ++s) { bv[r][s] = -FLT_MAX; bi[r][s] = 0x7fffffff; }

    for (int m0 = 0; m0 < 2048; m0 += 64) {
        __syncthreads();
#pragma unroll
        for (int it = 0; it < 16; ++it) {
            int idx = it * 256 + t;
            mt[idx >> 6][idx & 63] = hb[(size_t)(idx >> 6) * 2048 + m0 + (idx & 63)];
        }
        if (t < 64) mxx[t] = xx[(size_t)b * 2048 + m0 + t];
        __syncthreads();

        float acc[4][4];
#pragma unroll
        for (int r = 0; r < 4; ++r)
#pragma unroll
            for (int mm = 0; mm < 4; ++mm) acc[r][mm] = 0.f;

#pragma unroll
        for (int c = 0; c < 64; ++c) {
            float4 av = *(const float4*)&rows[c][rowb];
            float4 bb = *(const float4*)&mt[c][lj * 4];
            acc[0][0] += av.x * bb.x; acc[0][1] += av.x * bb.y; acc[0][2] += av.x * bb.z; acc[0][3] += av.x * bb.w;
            acc[1][0] += av.y * bb.x; acc[1][1] += av.y * bb.y; acc[1][2] += av.y * bb.z; acc[1][3] += av.y * bb.w;
            acc[2][0] += av.z * bb.x; acc[2][1] += av.z * bb.y; acc[2][2] += av.z * bb.z; acc[2][3] += av.z * bb.w;
            acc[3][0] += av.w * bb.x; acc[3][1] += av.w * bb.y; acc[3][2] += av.w * bb.z; acc[3][3] += av.w * bb.w;
        }

#pragma unroll
        for (int r = 0; r < 4; ++r) {
            float pdv[4];
#pragma unroll
            for (int mm = 0; mm < 4; ++mm) {
                float sc = __fsub_rn(__fmul_rn(2.0f, acc[r][mm]), mxx[lj * 4 + mm]);
                pdv[mm] = __fsub_rn(sc, xn[r]);
            }
            float mx = fmaxf(fmaxf(pdv[0], pdv[1]), fmaxf(pdv[2], pdv[3]));
            if (mx >= bv[r][3]) {
#pragma unroll
                for (int mm = 0; mm < 4; ++mm)
                    ins4(pdv[mm], m0 + lj * 4 + mm, bv[r], bi[r]);
            }
        }
    }

    // ---- merge 16 lanes per row through LDS (reuse rows/mt) ----
    __syncthreads();
    float* cvf = &rows[0][0];
    int*   cif = (int*)&mt[0][0];
#pragma unroll
    for (int r = 0; r < 4; ++r)
#pragma unroll
        for (int s = 0; s < 4; ++s) {
            cvf[(rowb + r) * 64 + lj * 4 + s] = bv[r][s];
            cif[(rowb + r) * 64 + lj * 4 + s] = bi[r][s];
        }
    __syncthreads();
    if (t < 64) {
        float fv[4]; int fi[4];
#pragma unroll
        for (int s = 0; s < 4; ++s) { fv[s] = -FLT_MAX; fi[s] = 0x7fffffff; }
        for (int q = 0; q < 64; ++q)
            ins4(cvf[t * 64 + q], cif[t * 64 + q], fv, fi);
        int4 o4; o4.x = fi[0]; o4.y = fi[1]; o4.z = fi[2]; o4.w = fi[3];
        *(int4*)(idxout + ((size_t)b * 2048 + n0 + t) * 4) = o4;
    }
}

// xx[b,n] = sum_c h2[b,c,n]^2
__global__ __launch_bounds__(256) void xx_kernel(const float* __restrict__ h2, float* __restrict__ xx)
{
    int t = blockIdx.x * 256 + threadIdx.x;   // 16384
    int n = t & 2047, b = t >> 11;
    const float* hb = h2 + (size_t)b * 64 * 2048 + n;
    float a = 0.f;
#pragma unroll
    for (int c = 0; c < 64; ++c) { float v = hb[(size_t)c * 2048]; a += v * v; }
    xx[t] = a;
}

// g[b,c] = max_n h2[b,c,n]
__global__ __launch_bounds__(256) void gmax_kernel(const float* __restrict__ h2, float* __restrict__ g)
{
    const int c = blockIdx.x;   // 64
    const int b = blockIdx.y;   // 8
    const float* hb = h2 + ((size_t)b * 64 + c) * 2048;
    float m = -FLT_MAX;
    for (int n = threadIdx.x; n < 2048; n += 256) m = fmaxf(m, hb[n]);
#pragma unroll
    for (int off = 32; off > 0; off >>= 1) m = fmaxf(m, __shfl_down(m, off, 64));
    __shared__ float sm[4];
    if ((threadIdx.x & 63) == 0) sm[threadIdx.x >> 6] = m;
    __syncthreads();
    if (threadIdx.x == 0)
        g[(size_t)b * 64 + c] = fmaxf(fmaxf(sm[0], sm[1]), fmaxf(sm[2], sm[3]));
}

// feat2a[b,o,n,k] = relu((y[b,o,idx[b,n,k]] - y[b,o,n] + z[b,o,n])*s2a[o] + b2a[o])
__global__ __launch_bounds__(256) void feat2a_kernel(
    const float* __restrict__ y, const float* __restrict__ z, const int* __restrict__ idx,
    const float* __restrict__ s2a, const float* __restrict__ b2a, float* __restrict__ out)
{
    int t = blockIdx.x * 256 + threadIdx.x;   // 8*64*2048 = 1,048,576
    int n = t & 2047, o = (t >> 11) & 63, b = t >> 17;
    const float* yb = y + (size_t)(b * 64 + o) * 2048;
    const float* zb = z + (size_t)(b * 64 + o) * 2048;
    int4 id = *(const int4*)(idx + ((size_t)b * 2048 + n) * 4);
    float yn = yb[n], zn = zb[n];
    float base = zn - yn;
    float s = s2a[o], bb = b2a[o];
    float4 r;
    r.x = fmaxf((yb[id.x] + base) * s + bb, 0.f);
    r.y = fmaxf((yb[id.y] + base) * s + bb, 0.f);
    r.z = fmaxf((yb[id.z] + base) * s + bb, 0.f);
    r.w = fmaxf((yb[id.w] + base) * s + bb, 0.f);
    *(float4*)(out + ((size_t)(b * 64 + o) * 2048 + n) * 4) = r;
}

// g3b[b,:] = relu((W3b @ relu((W3a @ g)*s3a+b3a))*s3b+b3b)
__global__ __launch_bounds__(128) void gconv_kernel(
    const float* __restrict__ g,
    const float* __restrict__ W3a, const float* __restrict__ s3a, const float* __restrict__ b3a,
    const float* __restrict__ W3b, const float* __restrict__ s3b, const float* __restrict__ b3b,
    float* __restrict__ g3b)
{
    const int b = blockIdx.x;
    const int t = threadIdx.x;  // 128
    __shared__ float gl[64], ga[128];
    if (t < 64) gl[t] = g[(size_t)b * 64 + t];
    __syncthreads();
    float a = 0.f;
#pragma unroll
    for (int c = 0; c < 64; ++c) a += W3a[t * 64 + c] * gl[c];
    ga[t] = fmaxf(a * s3a[t] + b3a[t], 0.f);
    __syncthreads();
    float o = 0.f;
#pragma unroll
    for (int c = 0; c < 128; ++c) o += W3b[t * 128 + c] * ga[c];
    g3b[(size_t)b * 128 + t] = fmaxf(o * s3b[t] + b3b[t], 0.f);
}

// final[b, 64+j, n] = g3b[b, j]
__global__ __launch_bounds__(256) void bcast_kernel(const float* __restrict__ g3b, float* __restrict__ fin)
{
    int t = blockIdx.x * 256 + threadIdx.x;   // 8*128*2048 = 2,097,152
    int n = t & 2047, j = (t >> 11) & 127, b = t >> 18;
    fin[((size_t)b * 192 + 64 + j) * 2048 + n] = g3b[(size_t)b * 128 + j];
}

// out[b,o,n] = sum_c W4b[o,c]*h4[b,c,n] + b4b[o], o<3
__global__ __launch_bounds__(256) void conv4b_kernel(const float* __restrict__ h4,
    const float* __restrict__ W, const float* __restrict__ bias, float* __restrict__ out)
{
    __shared__ float Wl[768];
    for (int i = threadIdx.x; i < 768; i += 256) Wl[i] = W[i];
    __syncthreads();
    int t = blockIdx.x * 256 + threadIdx.x;   // 16384
    int n = t & 2047, b = t >> 11;
    const float* hb = h4 + (size_t)b * 256 * 2048 + n;
    float a0 = 0.f, a1 = 0.f, a2 = 0.f;
#pragma unroll 8
    for (int c = 0; c < 256; ++c) {
        float v = hb[(size_t)c * 2048];
        a0 += Wl[c] * v;
        a1 += Wl[256 + c] * v;
        a2 += Wl[512 + c] * v;
    }
    float* ob = out + (size_t)b * 3 * 2048 + n;
    ob[0]    = a0 + bias[0];
    ob[2048] = a1 + bias[1];
    ob[4096] = a2 + bias[2];
}

extern "C" void kernel_launch(void* const* d_in, const int* in_sizes, int n_in,
                              void* d_out, int out_size, void* d_ws, size_t ws_size,
                              hipStream_t stream)
{
    const float* x     = (const float*)d_in[0];
    const float* W_dup = (const float*)d_in[1];
    const float* s_dup = (const float*)d_in[2];
    const float* b_dup = (const float*)d_in[3];
    const float* W_c1  = (const float*)d_in[4];
    const float* s_c1  = (const float*)d_in[5];
    const float* b_c1  = (const float*)d_in[6];
    const float* W2a   = (const float*)d_in[7];
    const float* s2a   = (const float*)d_in[8];
    const float* b2a   = (const float*)d_in[9];
    const float* W2b   = (const float*)d_in[10];
    const float* s2b   = (const float*)d_in[11];
    const float* b2b   = (const float*)d_in[12];
    const float* W2c   = (const float*)d_in[13];
    const float* s2c   = (const float*)d_in[14];
    const float* b2c   = (const float*)d_in[15];
    const float* W3a   = (const float*)d_in[16];
    const float* s3a   = (const float*)d_in[17];
    const float* b3a   = (const float*)d_in[18];
    const float* W3b   = (const float*)d_in[19];
    const float* s3b   = (const float*)d_in[20];
    const float* b3b   = (const float*)d_in[21];
    const float* W4a   = (const float*)d_in[22];
    const float* b4a   = (const float*)d_in[23];
    const float* W4b   = (const float*)d_in[24];
    const float* b4b   = (const float*)d_in[25];

    if (ws_size < WS_FLOATS * sizeof(float)) return;  // fail loudly rather than corrupt

    float* ws   = (float*)d_ws;
    float* h1   = ws + OFF_H1;
    float* h2   = ws + OFF_H2;
    float* feat = ws + OFF_FEAT;   // feat2a, later h4
    float* fin  = ws + OFF_FINAL;
    float* y    = ws + OFF_Y;
    float* z    = ws + OFF_Z;
    float* xxb  = ws + OFF_XX;
    float* g    = ws + OFF_G;
    float* g3b  = ws + OFF_G3B;
    int*   idx  = (int*)(ws + OFF_IDX);
    float* out  = (float*)d_out;

    // 1) h1 = relu((W_dup @ x)*s+b)           (B,256,1024)
    gemm_cn<128, false><<<dim3(16, 4, 8), 256, 0, stream>>>(W_dup, 128, s_dup, b_dup, 1,
        x, (size_t)128 * 1024, 1024, h1, (size_t)256 * 1024, 1024);
    // 2) h2 = relu((W_c1 @ h1_reshaped)*s+b)  (B,64,2048); reshape is free (contiguous)
    gemm_cn<128, false><<<dim3(32, 1, 8), 256, 0, stream>>>(W_c1, 128, s_c1, b_c1, 1,
        h1, (size_t)128 * 2048, 2048, h2, (size_t)64 * 2048, 2048);
    // 3) xx + per-channel max
    xx_kernel<<<64, 256, 0, stream>>>(h2, xxb);
    gmax_kernel<<<dim3(64, 8), 256, 0, stream>>>(h2, g);
    // 4) fused pairwise-distance + top-4
    knn_topk<<<dim3(32, 8), 256, 0, stream>>>(h2, xxb, idx);
    // 5) y = W2a[:, :64] @ h2 ; z = W2a[:, 64:] @ h2   (raw GEMMs, no epilogue)
    gemm_cn<64, false><<<dim3(32, 1, 8), 256, 0, stream>>>(W2a, 128, nullptr, nullptr, 0,
        h2, (size_t)64 * 2048, 2048, y, (size_t)64 * 2048, 2048);
    gemm_cn<64, false><<<dim3(32, 1, 8), 256, 0, stream>>>(W2a + 64, 128, nullptr, nullptr, 0,
        h2, (size_t)64 * 2048, 2048, z, (size_t)64 * 2048, 2048);
    // 6) conv2a via gather:  relu((y[idx] - y + z)*s+b)  -> feat (B,64,2048,4)
    feat2a_kernel<<<4096, 256, 0, stream>>>(y, z, idx, s2a, b2a, feat);
    // 7) conv2b in-place on feat (each block owns disjoint n-columns; all global
    //    reads complete before epilogue writes)
    gemm_cn<64, false><<<dim3(128, 1, 8), 256, 0, stream>>>(W2b, 64, s2b, b2b, 1,
        feat, (size_t)64 * 8192, 8192, feat, (size_t)64 * 8192, 8192);
    // 8) conv2c + max over k -> final channels 0..63
    gemm_cn<64, true><<<dim3(128, 1, 8), 256, 0, stream>>>(W2c, 64, s2c, b2c, 1,
        feat, (size_t)64 * 8192, 8192, fin, (size_t)192 * 2048, 2048);
    // 9) tiny g-convs
    gconv_kernel<<<8, 128, 0, stream>>>(g, W3a, s3a, b3a, W3b, s3b, b3b, g3b);
    // 10) broadcast g3b into final channels 64..191
    bcast_kernel<<<8192, 256, 0, stream>>>(g3b, fin);
    // 11) h4 = relu(W4a @ final + b4a)  -> feat region (feat2a is dead)
    gemm_cn<192, false><<<dim3(32, 4, 8), 256, 0, stream>>>(W4a, 192, nullptr, b4a, 1,
        fin, (size_t)192 * 2048, 2048, feat, (size_t)256 * 2048, 2048);
    // 12) out = W4b @ h4 + b4b   (B,3,2048)
    conv4b_kernel<<<64, 256, 0, stream>>>(feat, W4b, b4b, out);
}

// Round 2
// 403.445 us; speedup vs baseline: 1.7867x; 1.7867x over previous
//
#include <hip/hip_runtime.h>
#include <float.h>

// ---------------- workspace layout (float offsets) ----------------
static constexpr size_t OFF_H1    = 0;          // 8*256*1024 = 2,097,152 (dead after h2)
static constexpr size_t OFF_H2    = 2097152;    // 8*64*2048  = 1,048,576
static constexpr size_t OFF_FEAT  = 3145728;    // feat2a/2b (8*64*2048*4) then h4 (8*256*2048) = 4,194,304
static constexpr size_t OFF_FINAL = 7340032;    // 8*192*2048 = 3,145,728
static constexpr size_t OFF_Y     = 10485760;   // 1,048,576
static constexpr size_t OFF_Z     = 11534336;   // 1,048,576
static constexpr size_t OFF_XX    = 12582912;   // 8*2048 = 16,384
static constexpr size_t OFF_G     = 12599296;   // 8*64 = 512
static constexpr size_t OFF_G3B   = 12599808;   // 8*128 = 1024
static constexpr size_t OFF_IDX   = 12600832;   // 8*2048*4 ints = 65,536
static constexpr size_t WS_FLOATS = 12666368;   // ~48.3 MB

// async 16B global->LDS. LDS dest = wave-uniform base + lane*16 (pass row base!)
__device__ __forceinline__ void gl_lds16(const float* g, float* l) {
    __builtin_amdgcn_global_load_lds(
        (const __attribute__((address_space(1))) void*)g,
        (__attribute__((address_space(3))) void*)l, 16, 0, 0);
}

// ---- top-4 insertion, (value desc, index asc); equal value keeps lower index ----
static __device__ __forceinline__ void ins4(float v, int m, float bv[4], int bi[4])
{
#pragma unroll
    for (int s = 0; s < 4; ++s) {
        bool better = (v > bv[s]) || (v == bv[s] && m < bi[s]);
        float tv = bv[s]; int tm = bi[s];
        bv[s] = better ? v : bv[s];
        bi[s] = better ? m : bi[s];
        v = better ? tv : v;
        m = better ? tm : m;
    }
}

// =================================================================
// Scalar-weight conv GEMM: out[b,o,n] = act((sum_c W[o,c]*in[b,c,n])*scale+bias)
// 256 thr = 4 waves; wave owns OW consecutive o; lanes cover 256 n (4 each).
// Weights through the scalar pipe (s_load + SGPR operand of v_fmac);
// input tile staged 64c x 256n (64 KB) via global_load_lds.
// MAXK: n-dim is (n,k) k-fastest; lane's 4 values = one n's 4 k -> max -> 1 float.
// =================================================================
template<int C, int OW, bool MAXK, bool RELU>
__global__ __launch_bounds__(256, 2) void conv_sw(
    const float* __restrict__ W, int wstride,
    const float* __restrict__ scale, const float* __restrict__ bias,
    const float* __restrict__ in, size_t ibstride, int irstride,
    float* __restrict__ out, size_t obstride, int orstride)
{
    const int t    = threadIdx.x;
    const int wu   = __builtin_amdgcn_readfirstlane(t >> 6);   // wave id, uniform
    const int lane = t & 63;
    const int n0   = blockIdx.x * 256;
    const int ob   = blockIdx.y * (OW * 4) + wu * OW;          // uniform per wave
    const int b    = blockIdx.z;
    const float* inb = in + (size_t)b * ibstride;
    float* outb = out + (size_t)b * obstride;

    __shared__ float lt[64][256];

    float acc[OW][4];
#pragma unroll
    for (int r = 0; r < OW; ++r)
#pragma unroll
        for (int j = 0; j < 4; ++j) acc[r][j] = 0.f;

    for (int c0 = 0; c0 < C; c0 += 64) {
        __syncthreads();   // previous chunk fully consumed
#pragma unroll
        for (int i = 0; i < 16; ++i) {
            const int c = i * 4 + wu;
            gl_lds16(inb + (size_t)(c0 + c) * irstride + n0 + lane * 4, &lt[c][0]);
        }
        __syncthreads();   // drains vmcnt (global_load_lds)

#pragma unroll 4
        for (int c = 0; c < 64; ++c) {
            float4 mv = *(const float4*)&lt[c][lane * 4];
#pragma unroll
            for (int r = 0; r < OW; ++r) {
                const float wv = W[(size_t)(ob + r) * wstride + c0 + c];  // uniform -> s_load
                acc[r][0] += wv * mv.x;
                acc[r][1] += wv * mv.y;
                acc[r][2] += wv * mv.z;
                acc[r][3] += wv * mv.w;
            }
        }
    }

#pragma unroll
    for (int r = 0; r < OW; ++r) {
        const int o = ob + r;
        const float s  = scale ? scale[o] : 1.0f;
        const float bb = bias  ? bias[o]  : 0.0f;
        if constexpr (MAXK) {
            float v = -FLT_MAX;
#pragma unroll
            for (int j = 0; j < 4; ++j)
                v = fmaxf(v, fmaxf(acc[r][j] * s + bb, 0.f));
            outb[(size_t)o * orstride + (n0 >> 2) + lane] = v;
        } else {
            float4 rr;
            rr.x = acc[r][0] * s + bb;
            rr.y = acc[r][1] * s + bb;
            rr.z = acc[r][2] * s + bb;
            rr.w = acc[r][3] * s + bb;
            if constexpr (RELU) {
                rr.x = fmaxf(rr.x, 0.f); rr.y = fmaxf(rr.y, 0.f);
                rr.z = fmaxf(rr.z, 0.f); rr.w = fmaxf(rr.w, 0.f);
            }
            *(float4*)(outb + (size_t)o * orstride + n0 + lane * 4) = rr;
        }
    }
}

// =================================================================
// Fused pairwise-distance + top-4 kNN, scalar-A variant.
// Block: 4 waves x 8 rows = 32 rows; full m-sweep in 256-wide LDS tiles.
// Rows enter via scalar pipe (h2[c][r0..r0+7] consecutive -> s_load),
// m-operand via ds_read_b128. pd order identical to round-1 (bit-exact).
// =================================================================
__global__ __launch_bounds__(256, 2) void knn_sw(const float* __restrict__ h2,
                                                 const float* __restrict__ xx,
                                                 int* __restrict__ idxout)
{
    const int t    = threadIdx.x;
    const int wu   = __builtin_amdgcn_readfirstlane(t >> 6);
    const int lane = t & 63;
    const int b    = blockIdx.y;
    const int nB   = blockIdx.x * 32;
    const int r0   = nB + wu * 8;            // uniform per wave
    const float* hb = h2 + (size_t)b * 64 * 2048;
    const float* xb = xx + (size_t)b * 2048;

    __shared__ float lt[64][256];            // m-tile [c][m]; reused for merge

    float xn[8];
#pragma unroll
    for (int r = 0; r < 8; ++r) xn[r] = xb[r0 + r];   // uniform -> SGPR

    float bv[8][4]; int bi[8][4];
#pragma unroll
    for (int r = 0; r < 8; ++r)
#pragma unroll
        for (int s = 0; s < 4; ++s) { bv[r][s] = -FLT_MAX; bi[r][s] = 0x7fffffff; }

    for (int m0 = 0; m0 < 2048; m0 += 256) {
        __syncthreads();
#pragma unroll
        for (int i = 0; i < 16; ++i) {
            const int c = i * 4 + wu;
            gl_lds16(hb + (size_t)c * 2048 + m0 + lane * 4, &lt[c][0]);
        }
        float4 xm = *(const float4*)&xb[m0 + lane * 4];
        __syncthreads();

        float acc[8][4];
#pragma unroll
        for (int r = 0; r < 8; ++r)
#pragma unroll
            for (int j = 0; j < 4; ++j) acc[r][j] = 0.f;

#pragma unroll 4
        for (int c = 0; c < 64; ++c) {
            float4 mv = *(const float4*)&lt[c][lane * 4];
#pragma unroll
            for (int r = 0; r < 8; ++r) {
                const float av = hb[(size_t)c * 2048 + r0 + r];   // uniform -> s_load
                acc[r][0] += av * mv.x;
                acc[r][1] += av * mv.y;
                acc[r][2] += av * mv.z;
                acc[r][3] += av * mv.w;
            }
        }

#pragma unroll
        for (int r = 0; r < 8; ++r) {
            float pdv[4];
            pdv[0] = __fsub_rn(__fsub_rn(__fmul_rn(2.0f, acc[r][0]), xm.x), xn[r]);
            pdv[1] = __fsub_rn(__fsub_rn(__fmul_rn(2.0f, acc[r][1]), xm.y), xn[r]);
            pdv[2] = __fsub_rn(__fsub_rn(__fmul_rn(2.0f, acc[r][2]), xm.z), xn[r]);
            pdv[3] = __fsub_rn(__fsub_rn(__fmul_rn(2.0f, acc[r][3]), xm.w), xn[r]);
            float mx = fmaxf(fmaxf(pdv[0], pdv[1]), fmaxf(pdv[2], pdv[3]));
            if (mx >= bv[r][3]) {
#pragma unroll
                for (int j = 0; j < 4; ++j)
                    ins4(pdv[j], m0 + lane * 4 + j, bv[r], bi[r]);
            }
        }
    }

    // ---- hierarchical merge through LDS (reuse lt: 32 KB vals + 32 KB idx) ----
    __syncthreads();
    float* mvf = &lt[0][0];            // [ (row*64 + lane)*4 + s ]
    int*   mif = (int*)&lt[32][0];
#pragma unroll
    for (int r = 0; r < 8; ++r) {
        const int row = wu * 8 + r;
#pragma unroll
        for (int s = 0; s < 4; ++s) {
            mvf[(row * 64 + lane) * 4 + s] = bv[r][s];
            mif[(row * 64 + lane) * 4 + s] = bi[r][s];
        }
    }
    __syncthreads();
    {   // stage 1: 8 threads per row, each merges 8 lanes' lists
        const int row = t >> 3, g = t & 7;
        float fv[4]; int fi[4];
#pragma unroll
        for (int s = 0; s < 4; ++s) { fv[s] = -FLT_MAX; fi[s] = 0x7fffffff; }
        for (int l = g * 8; l < g * 8 + 8; ++l)
#pragma unroll
            for (int s = 0; s < 4; ++s)
                ins4(mvf[(row * 64 + l) * 4 + s], mif[(row * 64 + l) * 4 + s], fv, fi);
        __syncthreads();
#pragma unroll
        for (int s = 0; s < 4; ++s) {
            mvf[(row * 64 + g) * 4 + s] = fv[s];
            mif[(row * 64 + g) * 4 + s] = fi[s];
        }
    }
    __syncthreads();
    if (t < 32) {
        float fv[4]; int fi[4];
#pragma unroll
        for (int s = 0; s < 4; ++s) { fv[s] = -FLT_MAX; fi[s] = 0x7fffffff; }
        for (int g = 0; g < 8; ++g)
#pragma unroll
            for (int s = 0; s < 4; ++s)
                ins4(mvf[(t * 64 + g) * 4 + s], mif[(t * 64 + g) * 4 + s], fv, fi);
        int4 o4; o4.x = fi[0]; o4.y = fi[1]; o4.z = fi[2]; o4.w = fi[3];
        *(int4*)(idxout + ((size_t)b * 2048 + nB + t) * 4) = o4;
    }
}

// xx[b,n] = sum_c h2[b,c,n]^2
__global__ __launch_bounds__(256) void xx_kernel(const float* __restrict__ h2, float* __restrict__ xx)
{
    int t = blockIdx.x * 256 + threadIdx.x;   // 16384
    int n = t & 2047, b = t >> 11;
    const float* hb = h2 + (size_t)b * 64 * 2048 + n;
    float a = 0.f;
#pragma unroll
    for (int c = 0; c < 64; ++c) { float v = hb[(size_t)c * 2048]; a += v * v; }
    xx[t] = a;
}

// g[b,c] = max_n h2[b,c,n]
__global__ __launch_bounds__(256) void gmax_kernel(const float* __restrict__ h2, float* __restrict__ g)
{
    const int c = blockIdx.x;   // 64
    const int b = blockIdx.y;   // 8
    const float* hb = h2 + ((size_t)b * 64 + c) * 2048;
    float m = -FLT_MAX;
    for (int n = threadIdx.x; n < 2048; n += 256) m = fmaxf(m, hb[n]);
#pragma unroll
    for (int off = 32; off > 0; off >>= 1) m = fmaxf(m, __shfl_down(m, off, 64));
    __shared__ float sm[4];
    if ((threadIdx.x & 63) == 0) sm[threadIdx.x >> 6] = m;
    __syncthreads();
    if (threadIdx.x == 0)
        g[(size_t)b * 64 + c] = fmaxf(fmaxf(sm[0], sm[1]), fmaxf(sm[2], sm[3]));
}

// feat2a[b,o,n,k] = relu((y[b,o,idx[b,n,k]] - y[b,o,n] + z[b,o,n])*s2a[o] + b2a[o])
__global__ __launch_bounds__(256) void feat2a_kernel(
    const float* __restrict__ y, const float* __restrict__ z, const int* __restrict__ idx,
    const float* __restrict__ s2a, const float* __restrict__ b2a, float* __restrict__ out)
{
    int t = blockIdx.x * 256 + threadIdx.x;   // 8*64*2048 = 1,048,576
    int n = t & 2047, o = (t >> 11) & 63, b = t >> 17;
    const float* yb = y + (size_t)(b * 64 + o) * 2048;
    const float* zb = z + (size_t)(b * 64 + o) * 2048;
    int4 id = *(const int4*)(idx + ((size_t)b * 2048 + n) * 4);
    float yn = yb[n], zn = zb[n];
    float base = zn - yn;
    float s = s2a[o], bb = b2a[o];
    float4 r;
    r.x = fmaxf((yb[id.x] + base) * s + bb, 0.f);
    r.y = fmaxf((yb[id.y] + base) * s + bb, 0.f);
    r.z = fmaxf((yb[id.z] + base) * s + bb, 0.f);
    r.w = fmaxf((yb[id.w] + base) * s + bb, 0.f);
    *(float4*)(out + ((size_t)(b * 64 + o) * 2048 + n) * 4) = r;
}

// g3b[b,:] = relu((W3b @ relu((W3a @ g)*s3a+b3a))*s3b+b3b)
__global__ __launch_bounds__(128) void gconv_kernel(
    const float* __restrict__ g,
    const float* __restrict__ W3a, const float* __restrict__ s3a, const float* __restrict__ b3a,
    const float* __restrict__ W3b, const float* __restrict__ s3b, const float* __restrict__ b3b,
    float* __restrict__ g3b)
{
    const int b = blockIdx.x;
    const int t = threadIdx.x;  // 128
    __shared__ float gl[64], ga[128];
    if (t < 64) gl[t] = g[(size_t)b * 64 + t];
    __syncthreads();
    float a = 0.f;
#pragma unroll
    for (int c = 0; c < 64; ++c) a += W3a[t * 64 + c] * gl[c];
    ga[t] = fmaxf(a * s3a[t] + b3a[t], 0.f);
    __syncthreads();
    float o = 0.f;
#pragma unroll
    for (int c = 0; c < 128; ++c) o += W3b[t * 128 + c] * ga[c];
    g3b[(size_t)b * 128 + t] = fmaxf(o * s3b[t] + b3b[t], 0.f);
}

// final[b, 64+j, n] = g3b[b, j]
__global__ __launch_bounds__(256) void bcast_kernel(const float* __restrict__ g3b, float* __restrict__ fin)
{
    int t = blockIdx.x * 256 + threadIdx.x;   // 8*128*2048 = 2,097,152
    int n = t & 2047, j = (t >> 11) & 127, b = t >> 18;
    fin[((size_t)b * 192 + 64 + j) * 2048 + n] = g3b[(size_t)b * 128 + j];
}

// out[b,o,n] = sum_c W4b[o,c]*h4[b,c,n] + b4b[o], o<3
__global__ __launch_bounds__(256) void conv4b_kernel(const float* __restrict__ h4,
    const float* __restrict__ W, const float* __restrict__ bias, float* __restrict__ out)
{
    __shared__ float Wl[768];
    for (int i = threadIdx.x; i < 768; i += 256) Wl[i] = W[i];
    __syncthreads();
    int t = blockIdx.x * 256 + threadIdx.x;   // 16384
    int n = t & 2047, b = t >> 11;
    const float* hb = h4 + (size_t)b * 256 * 2048 + n;
    float a0 = 0.f, a1 = 0.f, a2 = 0.f;
#pragma unroll 8
    for (int c = 0; c < 256; ++c) {
        float v = hb[(size_t)c * 2048];
        a0 += Wl[c] * v;
        a1 += Wl[256 + c] * v;
        a2 += Wl[512 + c] * v;
    }
    float* ob = out + (size_t)b * 3 * 2048 + n;
    ob[0]    = a0 + bias[0];
    ob[2048] = a1 + bias[1];
    ob[4096] = a2 + bias[2];
}

extern "C" void kernel_launch(void* const* d_in, const int* in_sizes, int n_in,
                              void* d_out, int out_size, void* d_ws, size_t ws_size,
                              hipStream_t stream)
{
    const float* x     = (const float*)d_in[0];
    const float* W_dup = (const float*)d_in[1];
    const float* s_dup = (const float*)d_in[2];
    const float* b_dup = (const float*)d_in[3];
    const float* W_c1  = (const float*)d_in[4];
    const float* s_c1  = (const float*)d_in[5];
    const float* b_c1  = (const float*)d_in[6];
    const float* W2a   = (const float*)d_in[7];
    const float* s2a   = (const float*)d_in[8];
    const float* b2a   = (const float*)d_in[9];
    const float* W2b   = (const float*)d_in[10];
    const float* s2b   = (const float*)d_in[11];
    const float* b2b   = (const float*)d_in[12];
    const float* W2c   = (const float*)d_in[13];
    const float* s2c   = (const float*)d_in[14];
    const float* b2c   = (const float*)d_in[15];
    const float* W3a   = (const float*)d_in[16];
    const float* s3a   = (const float*)d_in[17];
    const float* b3a   = (const float*)d_in[18];
    const float* W3b   = (const float*)d_in[19];
    const float* s3b   = (const float*)d_in[20];
    const float* b3b   = (const float*)d_in[21];
    const float* W4a   = (const float*)d_in[22];
    const float* b4a   = (const float*)d_in[23];
    const float* W4b   = (const float*)d_in[24];
    const float* b4b   = (const float*)d_in[25];

    if (ws_size < WS_FLOATS * sizeof(float)) return;

    float* ws   = (float*)d_ws;
    float* h1   = ws + OFF_H1;
    float* h2   = ws + OFF_H2;
    float* feat = ws + OFF_FEAT;   // feat2a/2b, later h4
    float* fin  = ws + OFF_FINAL;
    float* y    = ws + OFF_Y;
    float* z    = ws + OFF_Z;
    float* xxb  = ws + OFF_XX;
    float* g    = ws + OFF_G;
    float* g3b  = ws + OFF_G3B;
    int*   idx  = (int*)(ws + OFF_IDX);
    float* out  = (float*)d_out;

    // 1) h1 = relu((W_dup @ x)*s+b)  (B,256,1024)
    conv_sw<128, 8, false, true><<<dim3(4, 8, 8), 256, 0, stream>>>(
        W_dup, 128, s_dup, b_dup, x, (size_t)128 * 1024, 1024, h1, (size_t)256 * 1024, 1024);
    // 2) h2 = relu((W_c1 @ h1r)*s+b) (B,64,2048); reshape (256,1024)->(128,2048) is free
    conv_sw<128, 8, false, true><<<dim3(8, 2, 8), 256, 0, stream>>>(
        W_c1, 128, s_c1, b_c1, h1, (size_t)128 * 2048, 2048, h2, (size_t)64 * 2048, 2048);
    // 3) xx + per-channel max
    xx_kernel<<<64, 256, 0, stream>>>(h2, xxb);
    gmax_kernel<<<dim3(64, 8), 256, 0, stream>>>(h2, g);
    // 4) fused pairwise-distance + top-4 (scalar-A)
    knn_sw<<<dim3(64, 8), 256, 0, stream>>>(h2, xxb, idx);
    // 5) y = W2a[:, :64] @ h2 ; z = W2a[:, 64:] @ h2
    conv_sw<64, 8, false, false><<<dim3(8, 2, 8), 256, 0, stream>>>(
        W2a, 128, nullptr, nullptr, h2, (size_t)64 * 2048, 2048, y, (size_t)64 * 2048, 2048);
    conv_sw<64, 8, false, false><<<dim3(8, 2, 8), 256, 0, stream>>>(
        W2a + 64, 128, nullptr, nullptr, h2, (size_t)64 * 2048, 2048, z, (size_t)64 * 2048, 2048);
    // 6) conv2a via gather: relu((y[idx]-y+z)*s+b) -> feat (B,64,2048,4)
    feat2a_kernel<<<4096, 256, 0, stream>>>(y, z, idx, s2a, b2a, feat);
    // 7) conv2b in-place (OW=16: block covers ALL 64 o; full tile staged before writes;
    //    blocks own disjoint n-columns -> safe)
    conv_sw<64, 16, false, true><<<dim3(32, 1, 8), 256, 0, stream>>>(
        W2b, 64, s2b, b2b, feat, (size_t)64 * 8192, 8192, feat, (size_t)64 * 8192, 8192);
    // 8) conv2c + max over k -> final channels 0..63
    conv_sw<64, 8, true, true><<<dim3(32, 2, 8), 256, 0, stream>>>(
        W2c, 64, s2c, b2c, feat, (size_t)64 * 8192, 8192, fin, (size_t)192 * 2048, 2048);
    // 9) tiny g-convs
    gconv_kernel<<<8, 128, 0, stream>>>(g, W3a, s3a, b3a, W3b, s3b, b3b, g3b);
    // 10) broadcast g3b into final channels 64..191
    bcast_kernel<<<8192, 256, 0, stream>>>(g3b, fin);
    // 11) h4 = relu(W4a @ final + b4a) -> feat region (feat2b dead)
    conv_sw<192, 8, false, true><<<dim3(8, 8, 8), 256, 0, stream>>>(
        W4a, 192, nullptr, b4a, fin, (size_t)192 * 2048, 2048, feat, (size_t)256 * 2048, 2048);
    // 12) out = W4b @ h4 + b4b  (B,3,2048)
    conv4b_kernel<<<64, 256, 0, stream>>>(feat, W4b, b4b, out);
}

// Round 3
// 362.418 us; speedup vs baseline: 1.9890x; 1.1132x over previous
//
#include <hip/hip_runtime.h>
#include <float.h>

typedef __attribute__((ext_vector_type(8))) short short8;   // 8 bf16 (4 VGPRs)
typedef __attribute__((ext_vector_type(4))) float f32x4;    // MFMA C/D

// ---------------- workspace layout (float offsets) ----------------
static constexpr size_t OFF_H1    = 0;          // 8*256*1024 = 2,097,152 (dead after h2; reused for h2T)
static constexpr size_t OFF_H2    = 2097152;    // 8*64*2048  = 1,048,576
static constexpr size_t OFF_FEAT  = 3145728;    // feat2a/2b (8*64*2048*4) then h4 (8*256*2048) = 4,194,304
static constexpr size_t OFF_FINAL = 7340032;    // 8*192*2048 = 3,145,728
static constexpr size_t OFF_Y     = 10485760;   // 1,048,576
static constexpr size_t OFF_Z     = 11534336;   // 1,048,576
static constexpr size_t OFF_XX    = 12582912;   // 8*2048 = 16,384
static constexpr size_t OFF_G     = 12599296;   // 8*64 = 512
static constexpr size_t OFF_G3B   = 12599808;   // 8*128 = 1024
static constexpr size_t OFF_IDX   = 12600832;   // 8*2048*4 ints = 65,536
static constexpr size_t WS_FLOATS = 12666368;   // ~48.3 MB
// h2T hi/lo live in the (dead) h1 region: 2 x 524,288 floats
static constexpr size_t OFF_THI   = OFF_H1;
static constexpr size_t OFF_TLO   = OFF_H1 + 524288;

// async 16B global->LDS. LDS dest = wave-uniform base + lane*16 (pass row base!)
__device__ __forceinline__ void gl_lds16(const float* g, float* l) {
    __builtin_amdgcn_global_load_lds(
        (const __attribute__((address_space(1))) void*)g,
        (__attribute__((address_space(3))) void*)l, 16, 0, 0);
}

// bf16 round-to-nearest-even
__device__ __forceinline__ unsigned short f2bf(float x) {
    union { float f; unsigned int u; } v; v.f = x;
    unsigned int r = v.u + 0x7fffu + ((v.u >> 16) & 1u);
    return (unsigned short)(r >> 16);
}
__device__ __forceinline__ float bf2f(unsigned short h) {
    union { unsigned int u; float f; } v; v.u = ((unsigned int)h) << 16;
    return v.f;
}
__device__ __forceinline__ void split2(float x, unsigned short& h, unsigned short& l) {
    h = f2bf(x);
    l = f2bf(x - bf2f(h));
}

// ---- top-4 insertion, (value desc, index asc); equal value keeps lower index ----
static __device__ __forceinline__ void ins4(float v, int m, float bv[4], int bi[4])
{
#pragma unroll
    for (int s = 0; s < 4; ++s) {
        bool better = (v > bv[s]) || (v == bv[s] && m < bi[s]);
        float tv = bv[s]; int tm = bi[s];
        bv[s] = better ? v : bv[s];
        bi[s] = better ? m : bi[s];
        v = better ? tv : v;
        m = better ? tm : m;
    }
}

// =================================================================
// Transpose + bf16-split h2: in fp32 [b][64][2048] -> thi/tlo [b][2048][64]
// 64c x 64n tile per block via padded LDS.
// =================================================================
__global__ __launch_bounds__(256) void tsplit_h2(const float* __restrict__ h2,
                                                 unsigned short* __restrict__ thi,
                                                 unsigned short* __restrict__ tlo)
{
    const int b  = blockIdx.y;
    const int n0 = blockIdx.x * 64;
    const int t  = threadIdx.x;
    __shared__ float tile[64][65];
    const float* hb = h2 + (size_t)b * 64 * 2048;
#pragma unroll
    for (int i = 0; i < 16; ++i) {
        int c = i * 4 + (t >> 6), n = t & 63;
        tile[c][n] = hb[(size_t)c * 2048 + n0 + n];
    }
    __syncthreads();
    unsigned short* th = thi + (size_t)b * 2048 * 64;
    unsigned short* tl = tlo + (size_t)b * 2048 * 64;
#pragma unroll
    for (int i = 0; i < 16; ++i) {
        int n = i * 4 + (t >> 6), c = t & 63;
        unsigned short h, l;
        split2(tile[c][n], h, l);
        th[(size_t)(n0 + n) * 64 + c] = h;
        tl[(size_t)(n0 + n) * 64 + c] = l;
    }
}

// =================================================================
// Fused pairwise-distance + top-4 kNN via split-bf16 MFMA.
// pd[n,m] ~= 2*dot(h_n,h_m) - xx[n] - xx[m]  (approx to ~1e-5; exact-fl order
// impossible with MFMA, accepted risk).
// Block 256 = 4 waves: wave w -> (row-tile rt=w&1 -> 16 rows, m-half mh=w>>1).
// A-frag rows n0+j (j=lane&15), k=(lane>>4)*8+jj, 16B loads from h2T (hi/lo).
// B-frag cols m likewise. D: row(n-within-16)=(lane>>4)*4+reg, col(m)=lane&15.
// 4 split products (hh,hl,lh,ll) chained into one fp32 acc.
// =================================================================
__global__ __launch_bounds__(256) void knn_mfma(const unsigned short* __restrict__ thi,
                                                const unsigned short* __restrict__ tlo,
                                                const float* __restrict__ xx,
                                                int* __restrict__ idxout)
{
    const int b    = blockIdx.y;
    const int t    = threadIdx.x;
    const int lane = t & 63;
    const int j    = lane & 15;
    const int q    = lane >> 4;
    const int w    = t >> 6;
    const int rt   = w & 1;
    const int mh   = w >> 1;
    const int n0   = blockIdx.x * 32 + rt * 16;

    const unsigned short* th = thi + (size_t)b * 2048 * 64;
    const unsigned short* tl = tlo + (size_t)b * 2048 * 64;
    const float* xb = xx + (size_t)b * 2048;

    // A fragments (rows), loaded once: 2 k-steps x {hi,lo}
    short8 ah0 = *(const short8*)(th + (size_t)(n0 + j) * 64 + q * 8);
    short8 ah1 = *(const short8*)(th + (size_t)(n0 + j) * 64 + 32 + q * 8);
    short8 al0 = *(const short8*)(tl + (size_t)(n0 + j) * 64 + q * 8);
    short8 al1 = *(const short8*)(tl + (size_t)(n0 + j) * 64 + 32 + q * 8);

    float xn[4];
#pragma unroll
    for (int r = 0; r < 4; ++r) xn[r] = xb[n0 + q * 4 + r];

    float bv[4][4]; int bi[4][4];
#pragma unroll
    for (int r = 0; r < 4; ++r)
#pragma unroll
        for (int s = 0; s < 4; ++s) { bv[r][s] = -FLT_MAX; bi[r][s] = 0x7fffffff; }

    const int mbeg = mh * 1024;
    for (int m0 = mbeg; m0 < mbeg + 1024; m0 += 64) {
        f32x4 acc[4];
        short8 bh0[4], bl0[4], bh1[4], bl1[4];
#pragma unroll
        for (int sub = 0; sub < 4; ++sub) {
            const size_t row = (size_t)(m0 + sub * 16 + j) * 64;
            bh0[sub] = *(const short8*)(th + row + q * 8);
            bh1[sub] = *(const short8*)(th + row + 32 + q * 8);
            bl0[sub] = *(const short8*)(tl + row + q * 8);
            bl1[sub] = *(const short8*)(tl + row + 32 + q * 8);
            acc[sub] = (f32x4){0.f, 0.f, 0.f, 0.f};
        }
        float xm[4];
#pragma unroll
        for (int sub = 0; sub < 4; ++sub) xm[sub] = xb[m0 + sub * 16 + j];

#pragma unroll
        for (int sub = 0; sub < 4; ++sub) {
            acc[sub] = __builtin_amdgcn_mfma_f32_16x16x32_bf16(ah0, bh0[sub], acc[sub], 0, 0, 0);
            acc[sub] = __builtin_amdgcn_mfma_f32_16x16x32_bf16(ah0, bl0[sub], acc[sub], 0, 0, 0);
            acc[sub] = __builtin_amdgcn_mfma_f32_16x16x32_bf16(al0, bh0[sub], acc[sub], 0, 0, 0);
            acc[sub] = __builtin_amdgcn_mfma_f32_16x16x32_bf16(al0, bl0[sub], acc[sub], 0, 0, 0);
            acc[sub] = __builtin_amdgcn_mfma_f32_16x16x32_bf16(ah1, bh1[sub], acc[sub], 0, 0, 0);
            acc[sub] = __builtin_amdgcn_mfma_f32_16x16x32_bf16(ah1, bl1[sub], acc[sub], 0, 0, 0);
            acc[sub] = __builtin_amdgcn_mfma_f32_16x16x32_bf16(al1, bh1[sub], acc[sub], 0, 0, 0);
            acc[sub] = __builtin_amdgcn_mfma_f32_16x16x32_bf16(al1, bl1[sub], acc[sub], 0, 0, 0);
        }

        float pds[4][4];   // [sub][r]
#pragma unroll
        for (int sub = 0; sub < 4; ++sub)
#pragma unroll
            for (int r = 0; r < 4; ++r)
                pds[sub][r] = __builtin_fmaf(2.f, acc[sub][r], -xn[r]) - xm[sub];

#pragma unroll
        for (int r = 0; r < 4; ++r) {
            float mx = fmaxf(fmaxf(pds[0][r], pds[1][r]), fmaxf(pds[2][r], pds[3][r]));
            if (mx >= bv[r][3]) {
#pragma unroll
                for (int sub = 0; sub < 4; ++sub)
                    ins4(pds[sub][r], m0 + sub * 16 + j, bv[r], bi[r]);
            }
        }
    }

    // ---- merge: lane lists -> per-row top-4 across 16 lanes x 2 halves ----
    __shared__ float lv[32][32][4];
    __shared__ int   li[32][32][4];
#pragma unroll
    for (int r = 0; r < 4; ++r) {
        const int row = rt * 16 + q * 4 + r;
        const int slot = mh * 16 + j;
#pragma unroll
        for (int s = 0; s < 4; ++s) { lv[row][slot][s] = bv[r][s]; li[row][slot][s] = bi[r][s]; }
    }
    __syncthreads();
    {   // stage A: 8 threads/row, each merges 4 slots -> slot g*4
        const int row = t >> 3, g = t & 7;
        float fv[4]; int fi[4];
#pragma unroll
        for (int s = 0; s < 4; ++s) { fv[s] = -FLT_MAX; fi[s] = 0x7fffffff; }
        for (int sl = g * 4; sl < g * 4 + 4; ++sl)
#pragma unroll
            for (int s = 0; s < 4; ++s) ins4(lv[row][sl][s], li[row][sl][s], fv, fi);
#pragma unroll
        for (int s = 0; s < 4; ++s) { lv[row][g * 4][s] = fv[s]; li[row][g * 4][s] = fi[s]; }
    }
    __syncthreads();
    if (t < 32) {
        float fv[4]; int fi[4];
#pragma unroll
        for (int s = 0; s < 4; ++s) { fv[s] = -FLT_MAX; fi[s] = 0x7fffffff; }
        for (int g = 0; g < 8; ++g)
#pragma unroll
            for (int s = 0; s < 4; ++s) ins4(lv[t][g * 4][s], li[t][g * 4][s], fv, fi);
        const int n = blockIdx.x * 32 + t;
        int4 o4; o4.x = fi[0]; o4.y = fi[1]; o4.z = fi[2]; o4.w = fi[3];
        *(int4*)(idxout + ((size_t)b * 2048 + n) * 4) = o4;
    }
}

// =================================================================
// Scalar-weight conv GEMM (unchanged from round 2)
// =================================================================
template<int C, int OW, bool MAXK, bool RELU>
__global__ __launch_bounds__(256, 2) void conv_sw(
    const float* __restrict__ W, int wstride,
    const float* __restrict__ scale, const float* __restrict__ bias,
    const float* __restrict__ in, size_t ibstride, int irstride,
    float* __restrict__ out, size_t obstride, int orstride)
{
    const int t    = threadIdx.x;
    const int wu   = __builtin_amdgcn_readfirstlane(t >> 6);
    const int lane = t & 63;
    const int n0   = blockIdx.x * 256;
    const int ob   = blockIdx.y * (OW * 4) + wu * OW;
    const int b    = blockIdx.z;
    const float* inb = in + (size_t)b * ibstride;
    float* outb = out + (size_t)b * obstride;

    __shared__ float lt[64][256];

    float acc[OW][4];
#pragma unroll
    for (int r = 0; r < OW; ++r)
#pragma unroll
        for (int jj = 0; jj < 4; ++jj) acc[r][jj] = 0.f;

    for (int c0 = 0; c0 < C; c0 += 64) {
        __syncthreads();
#pragma unroll
        for (int i = 0; i < 16; ++i) {
            const int c = i * 4 + wu;
            gl_lds16(inb + (size_t)(c0 + c) * irstride + n0 + lane * 4, &lt[c][0]);
        }
        __syncthreads();

#pragma unroll 4
        for (int c = 0; c < 64; ++c) {
            float4 mv = *(const float4*)&lt[c][lane * 4];
#pragma unroll
            for (int r = 0; r < OW; ++r) {
                const float wv = W[(size_t)(ob + r) * wstride + c0 + c];
                acc[r][0] += wv * mv.x;
                acc[r][1] += wv * mv.y;
                acc[r][2] += wv * mv.z;
                acc[r][3] += wv * mv.w;
            }
        }
    }

#pragma unroll
    for (int r = 0; r < OW; ++r) {
        const int o = ob + r;
        const float s  = scale ? scale[o] : 1.0f;
        const float bb = bias  ? bias[o]  : 0.0f;
        if constexpr (MAXK) {
            float v = -FLT_MAX;
#pragma unroll
            for (int jj = 0; jj < 4; ++jj)
                v = fmaxf(v, fmaxf(acc[r][jj] * s + bb, 0.f));
            outb[(size_t)o * orstride + (n0 >> 2) + lane] = v;
        } else {
            float4 rr;
            rr.x = acc[r][0] * s + bb;
            rr.y = acc[r][1] * s + bb;
            rr.z = acc[r][2] * s + bb;
            rr.w = acc[r][3] * s + bb;
            if constexpr (RELU) {
                rr.x = fmaxf(rr.x, 0.f); rr.y = fmaxf(rr.y, 0.f);
                rr.z = fmaxf(rr.z, 0.f); rr.w = fmaxf(rr.w, 0.f);
            }
            *(float4*)(outb + (size_t)o * orstride + n0 + lane * 4) = rr;
        }
    }
}

// xx[b,n] = sum_c h2[b,c,n]^2
__global__ __launch_bounds__(256) void xx_kernel(const float* __restrict__ h2, float* __restrict__ xx)
{
    int t = blockIdx.x * 256 + threadIdx.x;
    int n = t & 2047, b = t >> 11;
    const float* hb = h2 + (size_t)b * 64 * 2048 + n;
    float a = 0.f;
#pragma unroll
    for (int c = 0; c < 64; ++c) { float v = hb[(size_t)c * 2048]; a += v * v; }
    xx[t] = a;
}

// g[b,c] = max_n h2[b,c,n]
__global__ __launch_bounds__(256) void gmax_kernel(const float* __restrict__ h2, float* __restrict__ g)
{
    const int c = blockIdx.x;
    const int b = blockIdx.y;
    const float* hb = h2 + ((size_t)b * 64 + c) * 2048;
    float m = -FLT_MAX;
    for (int n = threadIdx.x; n < 2048; n += 256) m = fmaxf(m, hb[n]);
#pragma unroll
    for (int off = 32; off > 0; off >>= 1) m = fmaxf(m, __shfl_down(m, off, 64));
    __shared__ float sm[4];
    if ((threadIdx.x & 63) == 0) sm[threadIdx.x >> 6] = m;
    __syncthreads();
    if (threadIdx.x == 0)
        g[(size_t)b * 64 + c] = fmaxf(fmaxf(sm[0], sm[1]), fmaxf(sm[2], sm[3]));
}

// feat2a[b,o,n,k] = relu((y[b,o,idx[b,n,k]] - y[b,o,n] + z[b,o,n])*s2a[o] + b2a[o])
__global__ __launch_bounds__(256) void feat2a_kernel(
    const float* __restrict__ y, const float* __restrict__ z, const int* __restrict__ idx,
    const float* __restrict__ s2a, const float* __restrict__ b2a, float* __restrict__ out)
{
    int t = blockIdx.x * 256 + threadIdx.x;
    int n = t & 2047, o = (t >> 11) & 63, b = t >> 17;
    const float* yb = y + (size_t)(b * 64 + o) * 2048;
    const float* zb = z + (size_t)(b * 64 + o) * 2048;
    int4 id = *(const int4*)(idx + ((size_t)b * 2048 + n) * 4);
    float yn = yb[n], zn = zb[n];
    float base = zn - yn;
    float s = s2a[o], bb = b2a[o];
    float4 r;
    r.x = fmaxf((yb[id.x] + base) * s + bb, 0.f);
    r.y = fmaxf((yb[id.y] + base) * s + bb, 0.f);
    r.z = fmaxf((yb[id.z] + base) * s + bb, 0.f);
    r.w = fmaxf((yb[id.w] + base) * s + bb, 0.f);
    *(float4*)(out + ((size_t)(b * 64 + o) * 2048 + n) * 4) = r;
}

// g3b[b,:] = relu((W3b @ relu((W3a @ g)*s3a+b3a))*s3b+b3b)
__global__ __launch_bounds__(128) void gconv_kernel(
    const float* __restrict__ g,
    const float* __restrict__ W3a, const float* __restrict__ s3a, const float* __restrict__ b3a,
    const float* __restrict__ W3b, const float* __restrict__ s3b, const float* __restrict__ b3b,
    float* __restrict__ g3b)
{
    const int b = blockIdx.x;
    const int t = threadIdx.x;
    __shared__ float gl[64], ga[128];
    if (t < 64) gl[t] = g[(size_t)b * 64 + t];
    __syncthreads();
    float a = 0.f;
#pragma unroll
    for (int c = 0; c < 64; ++c) a += W3a[t * 64 + c] * gl[c];
    ga[t] = fmaxf(a * s3a[t] + b3a[t], 0.f);
    __syncthreads();
    float o = 0.f;
#pragma unroll
    for (int c = 0; c < 128; ++c) o += W3b[t * 128 + c] * ga[c];
    g3b[(size_t)b * 128 + t] = fmaxf(o * s3b[t] + b3b[t], 0.f);
}

// final[b, 64+j, n] = g3b[b, j]
__global__ __launch_bounds__(256) void bcast_kernel(const float* __restrict__ g3b, float* __restrict__ fin)
{
    int t = blockIdx.x * 256 + threadIdx.x;
    int n = t & 2047, jj = (t >> 11) & 127, b = t >> 18;
    fin[((size_t)b * 192 + 64 + jj) * 2048 + n] = g3b[(size_t)b * 128 + jj];
}

// out[b,o,n] = sum_c W4b[o,c]*h4[b,c,n] + b4b[o], o<3
__global__ __launch_bounds__(256) void conv4b_kernel(const float* __restrict__ h4,
    const float* __restrict__ W, const float* __restrict__ bias, float* __restrict__ out)
{
    __shared__ float Wl[768];
    for (int i = threadIdx.x; i < 768; i += 256) Wl[i] = W[i];
    __syncthreads();
    int t = blockIdx.x * 256 + threadIdx.x;
    int n = t & 2047, b = t >> 11;
    const float* hb = h4 + (size_t)b * 256 * 2048 + n;
    float a0 = 0.f, a1 = 0.f, a2 = 0.f;
#pragma unroll 8
    for (int c = 0; c < 256; ++c) {
        float v = hb[(size_t)c * 2048];
        a0 += Wl[c] * v;
        a1 += Wl[256 + c] * v;
        a2 += Wl[512 + c] * v;
    }
    float* ob = out + (size_t)b * 3 * 2048 + n;
    ob[0]    = a0 + bias[0];
    ob[2048] = a1 + bias[1];
    ob[4096] = a2 + bias[2];
}

extern "C" void kernel_launch(void* const* d_in, const int* in_sizes, int n_in,
                              void* d_out, int out_size, void* d_ws, size_t ws_size,
                              hipStream_t stream)
{
    const float* x     = (const float*)d_in[0];
    const float* W_dup = (const float*)d_in[1];
    const float* s_dup = (const float*)d_in[2];
    const float* b_dup = (const float*)d_in[3];
    const float* W_c1  = (const float*)d_in[4];
    const float* s_c1  = (const float*)d_in[5];
    const float* b_c1  = (const float*)d_in[6];
    const float* W2a   = (const float*)d_in[7];
    const float* s2a   = (const float*)d_in[8];
    const float* b2a   = (const float*)d_in[9];
    const float* W2b   = (const float*)d_in[10];
    const float* s2b   = (const float*)d_in[11];
    const float* b2b   = (const float*)d_in[12];
    const float* W2c   = (const float*)d_in[13];
    const float* s2c   = (const float*)d_in[14];
    const float* b2c   = (const float*)d_in[15];
    const float* W3a   = (const float*)d_in[16];
    const float* s3a   = (const float*)d_in[17];
    const float* b3a   = (const float*)d_in[18];
    const float* W3b   = (const float*)d_in[19];
    const float* s3b   = (const float*)d_in[20];
    const float* b3b   = (const float*)d_in[21];
    const float* W4a   = (const float*)d_in[22];
    const float* b4a   = (const float*)d_in[23];
    const float* W4b   = (const float*)d_in[24];
    const float* b4b   = (const float*)d_in[25];

    if (ws_size < WS_FLOATS * sizeof(float)) return;

    float* ws   = (float*)d_ws;
    float* h1   = ws + OFF_H1;
    float* h2   = ws + OFF_H2;
    float* feat = ws + OFF_FEAT;
    float* fin  = ws + OFF_FINAL;
    float* y    = ws + OFF_Y;
    float* z    = ws + OFF_Z;
    float* xxb  = ws + OFF_XX;
    float* g    = ws + OFF_G;
    float* g3b  = ws + OFF_G3B;
    int*   idx  = (int*)(ws + OFF_IDX);
    unsigned short* thi = (unsigned short*)(ws + OFF_THI);  // aliases h1 (dead by then)
    unsigned short* tlo = (unsigned short*)(ws + OFF_TLO);
    float* out  = (float*)d_out;

    // 1) h1 = relu((W_dup @ x)*s+b)  (B,256,1024)
    conv_sw<128, 8, false, true><<<dim3(4, 8, 8), 256, 0, stream>>>(
        W_dup, 128, s_dup, b_dup, x, (size_t)128 * 1024, 1024, h1, (size_t)256 * 1024, 1024);
    // 2) h2 = relu((W_c1 @ h1r)*s+b) (B,64,2048)
    conv_sw<128, 8, false, true><<<dim3(8, 2, 8), 256, 0, stream>>>(
        W_c1, 128, s_c1, b_c1, h1, (size_t)128 * 2048, 2048, h2, (size_t)64 * 2048, 2048);
    // 3) xx + per-channel max + transpose-split h2 (h1 now dead -> reuse region)
    xx_kernel<<<64, 256, 0, stream>>>(h2, xxb);
    gmax_kernel<<<dim3(64, 8), 256, 0, stream>>>(h2, g);
    tsplit_h2<<<dim3(32, 8), 256, 0, stream>>>(h2, thi, tlo);
    // 4) fused pairwise-distance + top-4 via split-bf16 MFMA
    knn_mfma<<<dim3(64, 8), 256, 0, stream>>>(thi, tlo, xxb, idx);
    // 5) y = W2a[:, :64] @ h2 ; z = W2a[:, 64:] @ h2
    conv_sw<64, 8, false, false><<<dim3(8, 2, 8), 256, 0, stream>>>(
        W2a, 128, nullptr, nullptr, h2, (size_t)64 * 2048, 2048, y, (size_t)64 * 2048, 2048);
    conv_sw<64, 8, false, false><<<dim3(8, 2, 8), 256, 0, stream>>>(
        W2a + 64, 128, nullptr, nullptr, h2, (size_t)64 * 2048, 2048, z, (size_t)64 * 2048, 2048);
    // 6) conv2a via gather: relu((y[idx]-y+z)*s+b) -> feat (B,64,2048,4)
    feat2a_kernel<<<4096, 256, 0, stream>>>(y, z, idx, s2a, b2a, feat);
    // 7) conv2b in-place
    conv_sw<64, 16, false, true><<<dim3(32, 1, 8), 256, 0, stream>>>(
        W2b, 64, s2b, b2b, feat, (size_t)64 * 8192, 8192, feat, (size_t)64 * 8192, 8192);
    // 8) conv2c + max over k -> final channels 0..63
    conv_sw<64, 8, true, true><<<dim3(32, 2, 8), 256, 0, stream>>>(
        W2c, 64, s2c, b2c, feat, (size_t)64 * 8192, 8192, fin, (size_t)192 * 2048, 2048);
    // 9) tiny g-convs
    gconv_kernel<<<8, 128, 0, stream>>>(g, W3a, s3a, b3a, W3b, s3b, b3b, g3b);
    // 10) broadcast g3b into final channels 64..191
    bcast_kernel<<<8192, 256, 0, stream>>>(g3b, fin);
    // 11) h4 = relu(W4a @ final + b4a) -> feat region
    conv_sw<192, 8, false, true><<<dim3(8, 8, 8), 256, 0, stream>>>(
        W4a, 192, nullptr, b4a, fin, (size_t)192 * 2048, 2048, feat, (size_t)256 * 2048, 2048);
    // 12) out = W4b @ h4 + b4b  (B,3,2048)
    conv4b_kernel<<<64, 256, 0, stream>>>(feat, W4b, b4b, out);
}